// Round 9
// baseline (566.479 us; speedup 1.0000x reference)
//
#include <hip/hip_runtime.h>

typedef unsigned short u16;
typedef unsigned int u32;
typedef __attribute__((ext_vector_type(4))) float f32x4;
typedef __attribute__((ext_vector_type(8))) short s16x8;

__device__ __forceinline__ u16 f2bf(float f) {
  union { float f; u32 u; } v; v.f = f;
  u32 u = v.u;
  return (u16)((u + 0x7fffu + ((u >> 16) & 1u)) >> 16);
}
__device__ __forceinline__ float bf2f(u16 b) {
  union { u32 u; float f; } v; v.u = ((u32)b) << 16;
  return v.f;
}
__device__ __forceinline__ float bf2f_s(short b) { return bf2f((u16)b); }
__device__ __forceinline__ float sigmoidf(float x) { return 1.0f / (1.0f + __expf(-x)); }

__device__ __forceinline__ void async16(const void* g, void* l) {
  __builtin_amdgcn_global_load_lds(
      (const __attribute__((address_space(1))) u32*)g,
      (__attribute__((address_space(3))) u32*)l, 16, 0, 0);
}

// ---------------------------------------------------------------------------
// prep: A fp32 -> bf16 in ws, and fp32 copy into output slot 1
// ---------------------------------------------------------------------------
__global__ __launch_bounds__(256) void prep_a(
    const float* __restrict__ A, u16* __restrict__ Abf, float* __restrict__ outA)
{
  const long i = ((long)blockIdx.x * 256 + threadIdx.x) * 4;
  float4 v = *(const float4*)(A + i);
  *(float4*)(outA + i) = v;
  ushort4 p;
  p.x = f2bf(v.x); p.y = f2bf(v.y); p.z = f2bf(v.z); p.w = f2bf(v.w);
  *(ushort4*)(Abf + i) = p;
}

// ---------------------------------------------------------------------------
// prep: build WcT [128][WK] bf16: rows 0..63 = (W0+W1)^T, 64..127 = W2^T,
// k = k3*CIN + cin, zero pad k >= 3*CIN. tw layout: [3][1][3][CIN][64]
// ---------------------------------------------------------------------------
__global__ __launch_bounds__(256) void prep_w(
    const float* __restrict__ tw, u16* __restrict__ WcT, int CIN, int WK)
{
  const int idx = blockIdx.x * 256 + threadIdx.x;
  if (idx >= 128 * WK) return;
  const int c = idx / WK;
  const int k = idx - c * WK;
  const int KR = CIN * 3;
  float v = 0.0f;
  if (k < KR) {
    const int k3 = k / CIN, cin = k - k3 * CIN;
    if (c < 64)
      v = tw[(k3 * CIN + cin) * 64 + c] + tw[(3 * CIN + k3 * CIN + cin) * 64 + c];
    else
      v = tw[(6 * CIN + k3 * CIN + cin) * 64 + (c - 64)];
  }
  WcT[idx] = f2bf(v);
}

// ---------------------------------------------------------------------------
// prep: fwT [16][896] bf16: fwT[p][k] = fw[k*12+p], zero for p >= 12
// ---------------------------------------------------------------------------
__global__ __launch_bounds__(256) void prep_fwt(
    const float* __restrict__ fw, u16* __restrict__ fwT)
{
  const int idx = blockIdx.x * 256 + threadIdx.x;
  if (idx >= 16 * 896) return;
  const int p = idx / 896;
  const int k = idx - p * 896;
  fwT[idx] = f2bf(p < 12 ? fw[k * 12 + p] : 0.0f);
}

// ---------------------------------------------------------------------------
// TB1 + theta1, full MFMA. x [16][2048][24][2] fp32. W1 [128][8] bf16 prepped.
// Output U1[(b*22+t)*16+p][n] bf16, packed b64 stores.
// ---------------------------------------------------------------------------
__global__ __launch_bounds__(256) void tb1_kernel(
    const float* __restrict__ x, const u16* __restrict__ W1,
    const float* __restrict__ bias, const float* __restrict__ th1,
    u16* __restrict__ U1)
{
  __shared__ float Bts[64], Bgs[64];
  __shared__ u16 t2buf[4][16 * 64];
  const int tid = threadIdx.x;
  if (tid < 64) { Bts[tid] = bias[tid] + bias[64 + tid]; Bgs[tid] = bias[128 + tid]; }
  const int lane = tid & 63, w = tid >> 6;
  const int lm = lane & 15, q = lane >> 4;
  const int b = blockIdx.y, t = blockIdx.z;
  const int n0 = blockIdx.x * 256 + w * 64;

  s16x8 wfrag[8];
#pragma unroll
  for (int mt = 0; mt < 8; mt++) {
    wfrag[mt] = (s16x8){0, 0, 0, 0, 0, 0, 0, 0};
    if (q == 0) wfrag[mt] = *(const s16x8*)(W1 + (mt * 16 + lm) * 8);
  }
  s16x8 tfrag[2];
#pragma unroll
  for (int kk = 0; kk < 2; kk++)
#pragma unroll
    for (int j = 0; j < 8; j++)
      tfrag[kk][j] = (short)f2bf(th1[(kk * 32 + q * 8 + j) * 16 + lm]);

  float xv[4][6];
  if (q == 0) {
#pragma unroll
    for (int nt = 0; nt < 4; nt++) {
      const float* xp = x + ((long)(b * 2048 + n0 + nt * 16 + lm) * 24 + t) * 2;
#pragma unroll
      for (int j = 0; j < 6; j++) xv[nt][j] = xp[j];
    }
  }
  __syncthreads();
  float bt4[4][4], bg4[4][4];
#pragma unroll
  for (int mt = 0; mt < 4; mt++)
#pragma unroll
    for (int r = 0; r < 4; r++) {
      bt4[mt][r] = Bts[mt * 16 + q * 4 + r];
      bg4[mt][r] = Bgs[mt * 16 + q * 4 + r];
    }

  u16* myt2 = t2buf[w];
  const long orowbase = (long)((b * 22 + t) * 16) << 11;

#pragma unroll
  for (int nt = 0; nt < 4; nt++) {
    s16x8 pfrag = (s16x8){0, 0, 0, 0, 0, 0, 0, 0};
    if (q == 0) {
#pragma unroll
      for (int j = 0; j < 6; j++) pfrag[j] = (short)f2bf(xv[nt][j]);
    }
    f32x4 acc1[8];
#pragma unroll
    for (int mt = 0; mt < 8; mt++) acc1[mt] = f32x4{0.f, 0.f, 0.f, 0.f};
#pragma unroll
    for (int mt = 0; mt < 8; mt++)
      acc1[mt] = __builtin_amdgcn_mfma_f32_16x16x32_bf16(wfrag[mt], pfrag, acc1[mt], 0, 0, 0);

#pragma unroll
    for (int mt = 0; mt < 4; mt++) {
      u32 pk[2];
      u16 pv[4];
#pragma unroll
      for (int r = 0; r < 4; r++) {
        const float temp = acc1[mt][r] + bt4[mt][r];
        const float ga = acc1[mt + 4][r] + bg4[mt][r];
        pv[r] = f2bf(fmaxf(temp * sigmoidf(ga), 0.0f));
      }
      pk[0] = (u32)pv[0] | ((u32)pv[1] << 16);
      pk[1] = (u32)pv[2] | ((u32)pv[3] << 16);
      const int g = (mt * 4 + q) >> 1, half = q & 1;
      *(uint2*)(myt2 + lm * 64 + (g ^ (lm & 7)) * 8 + half * 4) = make_uint2(pk[0], pk[1]);
    }

    f32x4 acc2 = f32x4{0.f, 0.f, 0.f, 0.f};
#pragma unroll
    for (int kk = 0; kk < 2; kk++) {
      s16x8 af = *(const s16x8*)(myt2 + lm * 64 + ((kk * 4 + q) ^ (lm & 7)) * 8);
      acc2 = __builtin_amdgcn_mfma_f32_16x16x32_bf16(af, tfrag[kk], acc2, 0, 0, 0);
    }
    u16 ov[4];
#pragma unroll
    for (int r = 0; r < 4; r++) ov[r] = f2bf(acc2[r]);
    *(uint2*)(U1 + orowbase + ((long)lm << 11) + n0 + nt * 16 + q * 4) =
        make_uint2((u32)ov[0] | ((u32)ov[1] << 16), (u32)ov[2] | ((u32)ov[3] << 16));
  }
}

// ---------------------------------------------------------------------------
// Spatial GEMM (NT): C[i,col] = sum_j A[i,j] * X[col, j]  (+ optional relu)
// ---------------------------------------------------------------------------
template <int RELU>
__global__ __launch_bounds__(256, 3) void sp_gemm(
    const u16* __restrict__ A, const u16* __restrict__ X,
    u16* __restrict__ C, int Ncols)
{
  __shared__ u16 ldsA[128 * 64];
  __shared__ u16 ldsB[128 * 64];
  const int lane = threadIdx.x & 63;
  const int w = threadIdx.x >> 6;

  const int ct = blockIdx.x >> 4;
  const int rt = blockIdx.x & 15;
  const int i0 = rt * 128;
  const int c0 = ct * 128;

  const int wm = w & 1, wn = w >> 1;
  const int lm = lane & 15, q = lane >> 4;

  f32x4 acc[4][4];
#pragma unroll
  for (int a = 0; a < 4; a++)
#pragma unroll
    for (int b2 = 0; b2 < 4; b2++) acc[a][b2] = f32x4{0.f, 0.f, 0.f, 0.f};

  const int srow = lane >> 3;
  const int sg = (lane & 7) ^ srow;
  const u16* gA = A + ((long)(i0 + w * 32 + srow) << 11) + sg * 8;
  const u16* gB = X + ((long)(c0 + w * 32 + srow) << 11) + sg * 8;
  u16* lA = ldsA + w * 2048;
  u16* lB = ldsB + w * 2048;

  for (int k0 = 0; k0 < 2048; k0 += 64) {
    __syncthreads();
#pragma unroll
    for (int j = 0; j < 4; j++) {
      async16(gA + j * 16384 + k0, lA + j * 512);
      async16(gB + j * 16384 + k0, lB + j * 512);
    }
    __syncthreads();
#pragma unroll
    for (int kk = 0; kk < 2; kk++) {
      const int ph = (kk * 4 + q) ^ (lm & 7);
      s16x8 af[4], bfr[4];
#pragma unroll
      for (int mt = 0; mt < 4; mt++)
        af[mt] = *(const s16x8*)(ldsA + (wm * 64 + mt * 16 + lm) * 64 + ph * 8);
#pragma unroll
      for (int nt = 0; nt < 4; nt++)
        bfr[nt] = *(const s16x8*)(ldsB + (wn * 64 + nt * 16 + lm) * 64 + ph * 8);
#pragma unroll
      for (int mt = 0; mt < 4; mt++)
#pragma unroll
        for (int nt = 0; nt < 4; nt++)
          acc[mt][nt] = __builtin_amdgcn_mfma_f32_16x16x32_bf16(af[mt], bfr[nt], acc[mt][nt], 0, 0, 0);
    }
  }

#pragma unroll
  for (int mt = 0; mt < 4; mt++) {
#pragma unroll
    for (int r = 0; r < 4; r++) {
      const long i = i0 + wm * 64 + mt * 16 + q * 4 + r;
      u16* crow = C + i * Ncols + c0 + wn * 64 + lm;
#pragma unroll
      for (int nt = 0; nt < 4; nt++) {
        float v = acc[mt][nt][r];
        if (RELU) v = fmaxf(v, 0.0f);
        crow[nt * 16] = f2bf(v);
      }
    }
  }
}

// ---------------------------------------------------------------------------
// CIN=64 conv (WK=192), BARRIER-FREE K-loop: A-fragments loaded directly
// from global (row = patch, 64B contiguous per lm across q) — no staging
// LDS, no syncs until the epilogue. Per wave: 8 pos-tiles x (6 loads +
// 12 MFMA); compiler software-pipelines with fine-grained vmcnt. Patch rows
// re-read 4x (per wave) from L1/L2 — cheap. LDS used only for epilogue.
// THETA==1 (TB3): fused theta2 epilogue -> U2[(bt)*16+p][n].
// THETA==0 (TB5): -> [n][16][TOUT][64].
// ---------------------------------------------------------------------------
template <int TIN, int THETA>
__global__ __launch_bounds__(256, 2) void conv192_k(
    const u16* __restrict__ in, const u16* __restrict__ WcT,
    const float* __restrict__ bias, const float* __restrict__ th,
    u16* __restrict__ out)
{
  constexpr int TOUT = TIN - 2;
  constexpr int ROWS = 16 * TIN * 64;
  constexpr int RST = THETA ? 88 : 72;
  __shared__ u16 lds[128 * RST];

  const int tid = threadIdx.x;
  const int lane = tid & 63;
  const int w = tid >> 6;
  const int lm = lane & 15, q = lane >> 4;
  const int pos0 = blockIdx.x << 7;
  const int n0 = pos0 & 2047;
  const int bt = pos0 >> 11;
  const int b = bt / TOUT, t = bt - b * TOUT;
  const int cb = (b * TIN + t) * 64;

  // weights -> registers (L2-resident after first block)
  s16x8 wf[2][6];
  {
    const u16* wp = WcT + (w * 16 + lm) * 192 + q * 8;
#pragma unroll
    for (int kk = 0; kk < 6; kk++) {
      wf[0][kk] = *(const s16x8*)(wp + kk * 32);            // temp couts
      wf[1][kk] = *(const s16x8*)(wp + 64 * 192 + kk * 32); // gate couts
    }
  }
  s16x8 tfrag[2];
  if (THETA) {
#pragma unroll
    for (int kk = 0; kk < 2; kk++)
#pragma unroll
      for (int j = 0; j < 8; j++)
        tfrag[kk][j] = (short)f2bf(th[(kk * 32 + q * 8 + j) * 16 + lm]);
  }
  const int c = w * 16 + lm;
  const float bsum = bias[c] + bias[64 + c];
  const float bg = bias[128 + c];

  // barrier-free main loop: per pos-tile, 6 direct global A-loads + 12 MFMA
  const u16* abase = in + (long)(n0 + lm) * ROWS + cb + q * 8;

  f32x4 acc[8][2];
#pragma unroll
  for (int m = 0; m < 8; m++) {
    acc[m][0] = f32x4{0.f, 0.f, 0.f, 0.f};
    acc[m][1] = f32x4{0.f, 0.f, 0.f, 0.f};
  }

#pragma unroll
  for (int mt = 0; mt < 8; mt++) {
    const u16* ap = abase + (long)mt * 16 * ROWS;
    s16x8 a[6];
#pragma unroll
    for (int kk = 0; kk < 6; kk++)
      a[kk] = *(const s16x8*)(ap + kk * 32);
#pragma unroll
    for (int kk = 0; kk < 6; kk++) {
      acc[mt][0] = __builtin_amdgcn_mfma_f32_16x16x32_bf16(a[kk], wf[0][kk], acc[mt][0], 0, 0, 0);
      acc[mt][1] = __builtin_amdgcn_mfma_f32_16x16x32_bf16(a[kk], wf[1][kk], acc[mt][1], 0, 0, 0);
    }
  }

  // epilogue: gate+relu -> LDS transpose -> stores (only barriers in kernel)
#pragma unroll
  for (int mt = 0; mt < 8; mt++) {
#pragma unroll
    for (int r = 0; r < 4; r++) {
      const int pos = mt * 16 + q * 4 + r;
      const float temp = acc[mt][0][r] + bsum;
      const float ga = acc[mt][1][r] + bg;
      lds[pos * RST + c] = f2bf(fmaxf(temp * sigmoidf(ga), 0.0f));
    }
  }
  __syncthreads();

  if (THETA == 0) {
    const int pos2 = tid >> 1, half = tid & 1;
    u16* orow = out + ((((long)(n0 + pos2) * 16 + b) * TOUT + t) << 6) + half * 32;
#pragma unroll
    for (int i = 0; i < 4; i++)
      *(uint4*)(orow + i * 8) = *(const uint4*)(lds + pos2 * 72 + half * 32 + i * 8);
  } else {
    // theta2 GEMM: U2[bt*16+p][n] = sum_m res[pos][m] * th[m][p]
    const long orowbase = (long)(bt * 16) << 11;
#pragma unroll
    for (int mt2 = 0; mt2 < 2; mt2++) {
      const int prow = w * 32 + mt2 * 16 + lm;
      f32x4 a2 = f32x4{0.f, 0.f, 0.f, 0.f};
#pragma unroll
      for (int kk = 0; kk < 2; kk++) {
        s16x8 af = *(const s16x8*)(lds + prow * 88 + kk * 32 + q * 8);
        a2 = __builtin_amdgcn_mfma_f32_16x16x32_bf16(af, tfrag[kk], a2, 0, 0, 0);
      }
      u16 ov[4];
#pragma unroll
      for (int r = 0; r < 4; r++) ov[r] = f2bf(a2[r]);
      *(uint2*)(out + orowbase + ((long)lm << 11) + n0 + w * 32 + mt2 * 16 + q * 4) =
          make_uint2((u32)ov[0] | ((u32)ov[1] << 16), (u32)ov[2] | ((u32)ov[3] << 16));
    }
  }
}

// ---------------------------------------------------------------------------
// CIN=16 conv (WK=64), DUO: one block = 2 consecutive bt, both staged up
// front; bt1's latency hidden behind bt0's compute+epilogue. Raw barriers
// keep bt1's loads in flight. Output [n][16][TOUT][64].
// ---------------------------------------------------------------------------
template <int TIN>
__global__ __launch_bounds__(256, 3) void conv64_duo(
    const u16* __restrict__ in, const u16* __restrict__ WcT,
    const float* __restrict__ bias, u16* __restrict__ out)
{
  constexpr int TOUT = TIN - 2;
  constexpr int ROWS = 16 * TIN * 16;
  __shared__ u16 lds[2 * 9216];

  const int tid = threadIdx.x;
  const int lane = tid & 63;
  const int w = tid >> 6;
  const int lm = lane & 15, q = lane >> 4;
  const int g = blockIdx.x;
  const int n0 = (g & 15) << 7;
  const int btp = g >> 4;

  // ---- group 1: weights + bias first ----
  s16x8 wf[2][2];
  {
    const u16* wp = WcT + (w * 16 + lm) * 64 + q * 8;
#pragma unroll
    for (int kk = 0; kk < 2; kk++) {
      wf[0][kk] = *(const s16x8*)(wp + kk * 32);
      wf[1][kk] = *(const s16x8*)(wp + 64 * 64 + kk * 32);
    }
  }
  const int c = w * 16 + lm;
  const float bsum = bias[c] + bias[64 + c];
  const float bg = bias[128 + c];

  // ---- group 2: stage bt0 then bt1 ----
  const int srow_off = lane >> 3;
  const int sgl = (lane & 7) ^ srow_off;
  int bs[2], ts[2];
  __builtin_amdgcn_sched_barrier(0);
#pragma unroll
  for (int h = 0; h < 2; h++) {
    const int bt = btp * 2 + h;
    const int b = bt / TOUT, t = bt - b * TOUT;
    bs[h] = b; ts[h] = t;
    const long cbase = (long)n0 * ROWS + (b * TIN + t) * 16;
#pragma unroll
    for (int i = 0; i < 4; i++) {
      const int row = i * 32 + w * 8 + srow_off;
      async16(in + cbase + (long)row * ROWS + sgl * 8,
              lds + h * 9216 + (i * 32 + w * 8) * 64);
    }
    __builtin_amdgcn_sched_barrier(0);
  }

#pragma unroll
  for (int h = 0; h < 2; h++) {
    if (h == 0) asm volatile("s_waitcnt vmcnt(4)" ::: "memory");  // bt0 landed
    else        asm volatile("s_waitcnt vmcnt(0)" ::: "memory");  // bt1 landed
    __builtin_amdgcn_s_barrier();

    f32x4 acc[8][2];
#pragma unroll
    for (int m = 0; m < 8; m++) {
      acc[m][0] = f32x4{0.f, 0.f, 0.f, 0.f};
      acc[m][1] = f32x4{0.f, 0.f, 0.f, 0.f};
    }
#pragma unroll
    for (int kk = 0; kk < 2; kk++) {
      const int ph = ((kk * 4 + q) ^ (lm & 7));
#pragma unroll
      for (int mt = 0; mt < 8; mt++) {
        s16x8 pf = *(const s16x8*)(lds + h * 9216 + (mt * 16 + lm) * 64 + ph * 8);
        acc[mt][0] = __builtin_amdgcn_mfma_f32_16x16x32_bf16(pf, wf[0][kk], acc[mt][0], 0, 0, 0);
        acc[mt][1] = __builtin_amdgcn_mfma_f32_16x16x32_bf16(pf, wf[1][kk], acc[mt][1], 0, 0, 0);
      }
    }
    __builtin_amdgcn_s_barrier();      // all waves done reading buf h

#pragma unroll
    for (int mt = 0; mt < 8; mt++) {
#pragma unroll
      for (int r = 0; r < 4; r++) {
        const int pos = mt * 16 + q * 4 + r;
        const float temp = acc[mt][0][r] + bsum;
        const float ga = acc[mt][1][r] + bg;
        lds[h * 9216 + pos * 72 + c] = f2bf(fmaxf(temp * sigmoidf(ga), 0.0f));
      }
    }
    asm volatile("s_waitcnt lgkmcnt(0)" ::: "memory");
    __builtin_amdgcn_s_barrier();      // transpose writes visible

    const int pos2 = tid >> 1, half = tid & 1;
    u16* orow = out + ((((long)(n0 + pos2) * 16 + bs[h]) * TOUT + ts[h]) << 6) + half * 32;
#pragma unroll
    for (int i = 0; i < 4; i++)
      *(uint4*)(orow + i * 8) = *(const uint4*)(lds + h * 9216 + pos2 * 72 + half * 32 + i * 8);
  }
}

// ---------------------------------------------------------------------------
// FC via MFMA: out4[b][n][p] = sum_k o3[(n*16+b)][k] * fwT[p][k] + fb[p]
// ---------------------------------------------------------------------------
__global__ __launch_bounds__(256) void fc_mfma(
    const u16* __restrict__ o3, const u16* __restrict__ fwT,
    const float* __restrict__ fb, float* __restrict__ out)
{
  __shared__ u16 sfw[16 * 896];
  const int tid = threadIdx.x;
#pragma unroll
  for (int i = 0; i < 7; i++)
    *(uint4*)(sfw + (i * 256 + tid) * 8) = *(const uint4*)(fwT + (i * 256 + tid) * 8);
  __syncthreads();

  const int lane = tid & 63, w = tid >> 6;
  const int lm = lane & 15, q = lane >> 4;
  const int row0 = blockIdx.x * 128 + w * 32;
  const u16* a0 = o3 + (long)(row0 + lm) * 896 + q * 8;
  const u16* bp = sfw + lm * 896 + q * 8;

  f32x4 acc0 = f32x4{0.f, 0.f, 0.f, 0.f};
  f32x4 acc1 = f32x4{0.f, 0.f, 0.f, 0.f};
#pragma unroll 7
  for (int kt = 0; kt < 28; kt++) {
    s16x8 af0 = *(const s16x8*)(a0 + kt * 32);
    s16x8 af1 = *(const s16x8*)(a0 + 16 * 896 + kt * 32);
    s16x8 bf = *(const s16x8*)(bp + kt * 32);
    acc0 = __builtin_amdgcn_mfma_f32_16x16x32_bf16(af0, bf, acc0, 0, 0, 0);
    acc1 = __builtin_amdgcn_mfma_f32_16x16x32_bf16(af1, bf, acc1, 0, 0, 0);
  }

  if (lm < 12) {
    const float bias = fb[lm];
#pragma unroll
    for (int r = 0; r < 4; r++) {
      const int row_a = row0 + q * 4 + r;
      out[((long)(row_a & 15) * 2048 + (row_a >> 4)) * 12 + lm] = acc0[r] + bias;
      const int row_b = row_a + 16;
      out[((long)(row_b & 15) * 2048 + (row_b >> 4)) * 12 + lm] = acc1[r] + bias;
    }
  }
}

// ---------------------------------------------------------------------------
extern "C" void kernel_launch(void* const* d_in, const int* in_sizes, int n_in,
                              void* d_out, int out_size, void* d_ws, size_t ws_size,
                              hipStream_t stream)
{
  const float* x    = (const float*)d_in[0];
  const float* A    = (const float*)d_in[1];
  const float* tb1w = (const float*)d_in[2];
  const float* tb1b = (const float*)d_in[3];
  const float* th1  = (const float*)d_in[4];
  const float* tb2w = (const float*)d_in[5];
  const float* tb2b = (const float*)d_in[6];
  const float* tb3w = (const float*)d_in[7];
  const float* tb3b = (const float*)d_in[8];
  const float* th2  = (const float*)d_in[9];
  const float* tb4w = (const float*)d_in[10];
  const float* tb4b = (const float*)d_in[11];
  const float* tb5w = (const float*)d_in[12];
  const float* tb5b = (const float*)d_in[13];
  const float* fw   = (const float*)d_in[14];
  const float* fb   = (const float*)d_in[15];
  float* out = (float*)d_out;

  char* ws = (char*)d_ws;
  u16* Abf  = (u16*)(ws + 0);            //  8,388,608 B
  u16* W2   = (u16*)(ws + 8388608);      //     16,384
  u16* W3   = (u16*)(ws + 8404992);      //     49,152
  u16* W4   = (u16*)(ws + 8454144);      //     16,384
  u16* W5   = (u16*)(ws + 8470528);      //     49,152
  u16* bufA = (u16*)(ws + 8519680);      // 92,274,688 (max live use 83.9 MB)
  u16* bufB = (u16*)(ws + 100794368);    // 92,274,688
  u16* W1   = (u16*)(ws + 8519680 + 88000000);  // 2 KB, in bufA tail slack
  u16* FWT  = (u16*)(ws + 8519680 + 88004096);  // 28,672 B, bufA tail slack

  prep_a<<<4096, 256, 0, stream>>>(A, Abf, out + 393216);
  prep_w<<<4, 256, 0, stream>>>(tb1w, W1, 2, 8);
  prep_w<<<32, 256, 0, stream>>>(tb2w, W2, 16, 64);
  prep_w<<<96, 256, 0, stream>>>(tb3w, W3, 64, 192);
  prep_w<<<32, 256, 0, stream>>>(tb4w, W4, 16, 64);
  prep_w<<<96, 256, 0, stream>>>(tb5w, W5, 64, 192);
  prep_fwt<<<56, 256, 0, stream>>>(fw, FWT);

  // ---- block 1:  U1 = TB1(x)*th1; t2 = relu(A*U1); out1 = TB2(t2)
  tb1_kernel<<<dim3(8, 16, 22), 256, 0, stream>>>(x, W1, tb1b, th1, bufA);
  sp_gemm<1><<<44 * 16, 256, 0, stream>>>(Abf, bufA, bufB, 5632);
  conv64_duo<22><<<2560, 256, 0, stream>>>(bufB, W2, tb2b, bufA);            // -> [n][16][20][64]
  // ---- block 2:  U2 = TB3(out1)*th2 (fused); t2 = relu(A*U2); TB4(t2)
  conv192_k<20, 1><<<4608, 256, 0, stream>>>(bufA, W3, tb3b, th2, bufB);     // -> U2 [(b,t,p)][n]
  sp_gemm<1><<<36 * 16, 256, 0, stream>>>(Abf, bufB, bufA, 4608);
  conv64_duo<18><<<2048, 256, 0, stream>>>(bufA, W4, tb4b, bufB);            // -> [n][16][16][64]
  // ---- tail
  conv192_k<16, 0><<<3584, 256, 0, stream>>>(bufB, W5, tb5b, nullptr, bufA); // -> [n][16][14][64]
  fc_mfma<<<256, 256, 0, stream>>>(bufA, FWT, fb, out);
}

// Round 10
// 409.796 us; speedup vs baseline: 1.3823x; 1.3823x over previous
//
#include <hip/hip_runtime.h>

typedef unsigned short u16;
typedef unsigned int u32;
typedef __attribute__((ext_vector_type(4))) float f32x4;
typedef __attribute__((ext_vector_type(8))) short s16x8;

__device__ __forceinline__ u16 f2bf(float f) {
  union { float f; u32 u; } v; v.f = f;
  u32 u = v.u;
  return (u16)((u + 0x7fffu + ((u >> 16) & 1u)) >> 16);
}
__device__ __forceinline__ float bf2f(u16 b) {
  union { u32 u; float f; } v; v.u = ((u32)b) << 16;
  return v.f;
}
__device__ __forceinline__ float bf2f_s(short b) { return bf2f((u16)b); }
__device__ __forceinline__ float sigmoidf(float x) { return 1.0f / (1.0f + __expf(-x)); }

__device__ __forceinline__ void async16(const void* g, void* l) {
  __builtin_amdgcn_global_load_lds(
      (const __attribute__((address_space(1))) u32*)g,
      (__attribute__((address_space(3))) u32*)l, 16, 0, 0);
}

// ---------------------------------------------------------------------------
// merged prep: one launch for A-cast/copy + 5 conv-weight preps + fwT.
// ---------------------------------------------------------------------------
__device__ __forceinline__ void prep_w_body(
    const float* __restrict__ tw, u16* __restrict__ WcT,
    int CIN, int WK, int idx)
{
  if (idx >= 128 * WK) return;
  const int c = idx / WK;
  const int k = idx - c * WK;
  const int KR = CIN * 3;
  float v = 0.0f;
  if (k < KR) {
    const int k3 = k / CIN, cin = k - k3 * CIN;
    if (c < 64)
      v = tw[(k3 * CIN + cin) * 64 + c] + tw[(3 * CIN + k3 * CIN + cin) * 64 + c];
    else
      v = tw[(6 * CIN + k3 * CIN + cin) * 64 + (c - 64)];
  }
  WcT[idx] = f2bf(v);
}

__global__ __launch_bounds__(256) void prep_all(
    const float* __restrict__ A, u16* __restrict__ Abf, float* __restrict__ outA,
    const float* __restrict__ tb1w, u16* __restrict__ W1,
    const float* __restrict__ tb2w, u16* __restrict__ W2,
    const float* __restrict__ tb3w, u16* __restrict__ W3,
    const float* __restrict__ tb4w, u16* __restrict__ W4,
    const float* __restrict__ tb5w, u16* __restrict__ W5,
    const float* __restrict__ fw, u16* __restrict__ FWT)
{
  const int bx = blockIdx.x;
  const int tid = threadIdx.x;
  if (bx < 4096) {
    const long i = ((long)bx * 256 + tid) * 4;
    float4 v = *(const float4*)(A + i);
    *(float4*)(outA + i) = v;
    ushort4 p;
    p.x = f2bf(v.x); p.y = f2bf(v.y); p.z = f2bf(v.z); p.w = f2bf(v.w);
    *(ushort4*)(Abf + i) = p;
  } else if (bx < 4100) {
    prep_w_body(tb1w, W1, 2, 8, (bx - 4096) * 256 + tid);
  } else if (bx < 4132) {
    prep_w_body(tb2w, W2, 16, 64, (bx - 4100) * 256 + tid);
  } else if (bx < 4228) {
    prep_w_body(tb3w, W3, 64, 192, (bx - 4132) * 256 + tid);
  } else if (bx < 4260) {
    prep_w_body(tb4w, W4, 16, 64, (bx - 4228) * 256 + tid);
  } else if (bx < 4356) {
    prep_w_body(tb5w, W5, 64, 192, (bx - 4260) * 256 + tid);
  } else {
    const int idx = (bx - 4356) * 256 + tid;
    if (idx < 16 * 896) {
      const int p = idx / 896, k = idx - p * 896;
      FWT[idx] = f2bf(p < 12 ? fw[k * 12 + p] : 0.0f);
    }
  }
}

// ---------------------------------------------------------------------------
// TB1 + theta1, full MFMA. x [16][2048][24][2] fp32. W1 [128][8] bf16 prepped.
// Output U1[(b*22+t)*16+p][n] bf16, packed b64 stores.
// ---------------------------------------------------------------------------
__global__ __launch_bounds__(256) void tb1_kernel(
    const float* __restrict__ x, const u16* __restrict__ W1,
    const float* __restrict__ bias, const float* __restrict__ th1,
    u16* __restrict__ U1)
{
  __shared__ float Bts[64], Bgs[64];
  __shared__ u16 t2buf[4][16 * 64];
  const int tid = threadIdx.x;
  if (tid < 64) { Bts[tid] = bias[tid] + bias[64 + tid]; Bgs[tid] = bias[128 + tid]; }
  const int lane = tid & 63, w = tid >> 6;
  const int lm = lane & 15, q = lane >> 4;
  const int b = blockIdx.y, t = blockIdx.z;
  const int n0 = blockIdx.x * 256 + w * 64;

  s16x8 wfrag[8];
#pragma unroll
  for (int mt = 0; mt < 8; mt++) {
    wfrag[mt] = (s16x8){0, 0, 0, 0, 0, 0, 0, 0};
    if (q == 0) wfrag[mt] = *(const s16x8*)(W1 + (mt * 16 + lm) * 8);
  }
  s16x8 tfrag[2];
#pragma unroll
  for (int kk = 0; kk < 2; kk++)
#pragma unroll
    for (int j = 0; j < 8; j++)
      tfrag[kk][j] = (short)f2bf(th1[(kk * 32 + q * 8 + j) * 16 + lm]);

  float xv[4][6];
  if (q == 0) {
#pragma unroll
    for (int nt = 0; nt < 4; nt++) {
      const float* xp = x + ((long)(b * 2048 + n0 + nt * 16 + lm) * 24 + t) * 2;
#pragma unroll
      for (int j = 0; j < 6; j++) xv[nt][j] = xp[j];
    }
  }
  __syncthreads();
  float bt4[4][4], bg4[4][4];
#pragma unroll
  for (int mt = 0; mt < 4; mt++)
#pragma unroll
    for (int r = 0; r < 4; r++) {
      bt4[mt][r] = Bts[mt * 16 + q * 4 + r];
      bg4[mt][r] = Bgs[mt * 16 + q * 4 + r];
    }

  u16* myt2 = t2buf[w];
  const long orowbase = (long)((b * 22 + t) * 16) << 11;

#pragma unroll
  for (int nt = 0; nt < 4; nt++) {
    s16x8 pfrag = (s16x8){0, 0, 0, 0, 0, 0, 0, 0};
    if (q == 0) {
#pragma unroll
      for (int j = 0; j < 6; j++) pfrag[j] = (short)f2bf(xv[nt][j]);
    }
    f32x4 acc1[8];
#pragma unroll
    for (int mt = 0; mt < 8; mt++) acc1[mt] = f32x4{0.f, 0.f, 0.f, 0.f};
#pragma unroll
    for (int mt = 0; mt < 8; mt++)
      acc1[mt] = __builtin_amdgcn_mfma_f32_16x16x32_bf16(wfrag[mt], pfrag, acc1[mt], 0, 0, 0);

#pragma unroll
    for (int mt = 0; mt < 4; mt++) {
      u32 pk[2];
      u16 pv[4];
#pragma unroll
      for (int r = 0; r < 4; r++) {
        const float temp = acc1[mt][r] + bt4[mt][r];
        const float ga = acc1[mt + 4][r] + bg4[mt][r];
        pv[r] = f2bf(fmaxf(temp * sigmoidf(ga), 0.0f));
      }
      pk[0] = (u32)pv[0] | ((u32)pv[1] << 16);
      pk[1] = (u32)pv[2] | ((u32)pv[3] << 16);
      const int g = (mt * 4 + q) >> 1, half = q & 1;
      *(uint2*)(myt2 + lm * 64 + (g ^ (lm & 7)) * 8 + half * 4) = make_uint2(pk[0], pk[1]);
    }

    f32x4 acc2 = f32x4{0.f, 0.f, 0.f, 0.f};
#pragma unroll
    for (int kk = 0; kk < 2; kk++) {
      s16x8 af = *(const s16x8*)(myt2 + lm * 64 + ((kk * 4 + q) ^ (lm & 7)) * 8);
      acc2 = __builtin_amdgcn_mfma_f32_16x16x32_bf16(af, tfrag[kk], acc2, 0, 0, 0);
    }
    u16 ov[4];
#pragma unroll
    for (int r = 0; r < 4; r++) ov[r] = f2bf(acc2[r]);
    *(uint2*)(U1 + orowbase + ((long)lm << 11) + n0 + nt * 16 + q * 4) =
        make_uint2((u32)ov[0] | ((u32)ov[1] << 16), (u32)ov[2] | ((u32)ov[3] << 16));
  }
}

// ---------------------------------------------------------------------------
// Spatial GEMM (NT): C[i,col] = sum_j A[i,j] * X[col, j]  (+ optional relu)
// ---------------------------------------------------------------------------
template <int RELU>
__global__ __launch_bounds__(256, 3) void sp_gemm(
    const u16* __restrict__ A, const u16* __restrict__ X,
    u16* __restrict__ C, int Ncols)
{
  __shared__ u16 ldsA[128 * 64];
  __shared__ u16 ldsB[128 * 64];
  const int lane = threadIdx.x & 63;
  const int w = threadIdx.x >> 6;

  const int ct = blockIdx.x >> 4;
  const int rt = blockIdx.x & 15;
  const int i0 = rt * 128;
  const int c0 = ct * 128;

  const int wm = w & 1, wn = w >> 1;
  const int lm = lane & 15, q = lane >> 4;

  f32x4 acc[4][4];
#pragma unroll
  for (int a = 0; a < 4; a++)
#pragma unroll
    for (int b2 = 0; b2 < 4; b2++) acc[a][b2] = f32x4{0.f, 0.f, 0.f, 0.f};

  const int srow = lane >> 3;
  const int sg = (lane & 7) ^ srow;
  const u16* gA = A + ((long)(i0 + w * 32 + srow) << 11) + sg * 8;
  const u16* gB = X + ((long)(c0 + w * 32 + srow) << 11) + sg * 8;
  u16* lA = ldsA + w * 2048;
  u16* lB = ldsB + w * 2048;

  for (int k0 = 0; k0 < 2048; k0 += 64) {
    __syncthreads();
#pragma unroll
    for (int j = 0; j < 4; j++) {
      async16(gA + j * 16384 + k0, lA + j * 512);
      async16(gB + j * 16384 + k0, lB + j * 512);
    }
    __syncthreads();
#pragma unroll
    for (int kk = 0; kk < 2; kk++) {
      const int ph = (kk * 4 + q) ^ (lm & 7);
      s16x8 af[4], bfr[4];
#pragma unroll
      for (int mt = 0; mt < 4; mt++)
        af[mt] = *(const s16x8*)(ldsA + (wm * 64 + mt * 16 + lm) * 64 + ph * 8);
#pragma unroll
      for (int nt = 0; nt < 4; nt++)
        bfr[nt] = *(const s16x8*)(ldsB + (wn * 64 + nt * 16 + lm) * 64 + ph * 8);
#pragma unroll
      for (int mt = 0; mt < 4; mt++)
#pragma unroll
        for (int nt = 0; nt < 4; nt++)
          acc[mt][nt] = __builtin_amdgcn_mfma_f32_16x16x32_bf16(af[mt], bfr[nt], acc[mt][nt], 0, 0, 0);
    }
  }

#pragma unroll
  for (int mt = 0; mt < 4; mt++) {
#pragma unroll
    for (int r = 0; r < 4; r++) {
      const long i = i0 + wm * 64 + mt * 16 + q * 4 + r;
      u16* crow = C + i * Ncols + c0 + wn * 64 + lm;
#pragma unroll
      for (int nt = 0; nt < 4; nt++) {
        float v = acc[mt][nt][r];
        if (RELU) v = fmaxf(v, 0.0f);
        crow[nt * 16] = f2bf(v);
      }
    }
  }
}

// ---------------------------------------------------------------------------
// CIN=64 conv (WK=192), R7 config (best measured): 128-pos blocks, all 3
// segments in flight, raw s_barrier + hand-counted s_waitcnt (vmcnt retires
// in issue order; group-1 VGPR loads first so 8/4/0 pick out seg 0/1/2).
// THETA==1 (TB3): fused theta2 epilogue -> U2[(bt)*16+p][n].
// THETA==0 (TB5): -> [n][16][TOUT][64].
// ---------------------------------------------------------------------------
template <int TIN, int THETA>
__global__ __launch_bounds__(256, 3) void conv192_k(
    const u16* __restrict__ in, const u16* __restrict__ WcT,
    const float* __restrict__ bias, const float* __restrict__ th,
    u16* __restrict__ out)
{
  constexpr int WK = 192;
  constexpr int KI = 6;
  constexpr int TOUT = TIN - 2;
  constexpr int ROWS = 16 * TIN * 64;
  constexpr int RST = THETA ? 88 : 72;
  __shared__ u16 lds[3 * 8192];

  const int tid = threadIdx.x;
  const int lane = tid & 63;
  const int w = tid >> 6;
  const int lm = lane & 15, q = lane >> 4;
  const int pos0 = blockIdx.x << 7;
  const int n0 = pos0 & 2047;
  const int bt = pos0 >> 11;
  const int b = bt / TOUT, t = bt - b * TOUT;
  const long cbase = (long)n0 * ROWS + (b * TIN + t) * 64;

  // ---- group 1: all non-stage global loads (retire before segments) ----
  s16x8 wf[2][KI];
  {
    const u16* wp = WcT + (w * 16 + lm) * WK + q * 8;
#pragma unroll
    for (int kk = 0; kk < KI; kk++) {
      wf[0][kk] = *(const s16x8*)(wp + kk * 32);
      wf[1][kk] = *(const s16x8*)(wp + 64 * WK + kk * 32);
    }
  }
  s16x8 tfrag[2];
  if (THETA) {
#pragma unroll
    for (int kk = 0; kk < 2; kk++)
#pragma unroll
      for (int j = 0; j < 8; j++)
        tfrag[kk][j] = (short)f2bf(th[(kk * 32 + q * 8 + j) * 16 + lm]);
  }
  const int c = w * 16 + lm;
  const float bsum = bias[c] + bias[64 + c];
  const float bg = bias[128 + c];

  // ---- group 2: segment staging, order-pinned ----
  const int srow_off = lane >> 3;
  const int sgl = (lane & 7) ^ srow_off;
  __builtin_amdgcn_sched_barrier(0);
#pragma unroll
  for (int s = 0; s < 3; s++) {
#pragma unroll
    for (int i = 0; i < 4; i++) {
      const int row = i * 32 + w * 8 + srow_off;
      async16(in + cbase + (long)row * ROWS + s * 64 + sgl * 8,
              lds + s * 8192 + (i * 32 + w * 8) * 64);
    }
    __builtin_amdgcn_sched_barrier(0);
  }

  f32x4 acc[8][2];
#pragma unroll
  for (int m = 0; m < 8; m++) {
    acc[m][0] = f32x4{0.f, 0.f, 0.f, 0.f};
    acc[m][1] = f32x4{0.f, 0.f, 0.f, 0.f};
  }

  auto compute = [&](int kk) {
    const int s = kk >> 1;
    const int ph = (((kk & 1) * 4 + q) ^ (lm & 7));
#pragma unroll
    for (int mt = 0; mt < 8; mt++) {
      s16x8 pf = *(const s16x8*)(lds + s * 8192 + (mt * 16 + lm) * 64 + ph * 8);
      acc[mt][0] = __builtin_amdgcn_mfma_f32_16x16x32_bf16(pf, wf[0][kk], acc[mt][0], 0, 0, 0);
      acc[mt][1] = __builtin_amdgcn_mfma_f32_16x16x32_bf16(pf, wf[1][kk], acc[mt][1], 0, 0, 0);
    }
  };

  asm volatile("s_waitcnt vmcnt(8)" ::: "memory");   // seg0 landed
  __builtin_amdgcn_s_barrier();
  compute(0); compute(1);
  asm volatile("s_waitcnt vmcnt(4)" ::: "memory");   // seg1 landed
  __builtin_amdgcn_s_barrier();
  compute(2); compute(3);
  asm volatile("s_waitcnt vmcnt(0)" ::: "memory");   // seg2 landed
  __builtin_amdgcn_s_barrier();
  compute(4); compute(5);

  __syncthreads();                    // all patch reads done; reuse LDS

#pragma unroll
  for (int mt = 0; mt < 8; mt++) {
#pragma unroll
    for (int r = 0; r < 4; r++) {
      const int pos = mt * 16 + q * 4 + r;
      const float temp = acc[mt][0][r] + bsum;
      const float ga = acc[mt][1][r] + bg;
      lds[pos * RST + c] = f2bf(fmaxf(temp * sigmoidf(ga), 0.0f));
    }
  }
  __syncthreads();

  if (THETA == 0) {
    const int pos2 = tid >> 1, half = tid & 1;
    u16* orow = out + ((((long)(n0 + pos2) * 16 + b) * TOUT + t) << 6) + half * 32;
#pragma unroll
    for (int i = 0; i < 4; i++)
      *(uint4*)(orow + i * 8) = *(const uint4*)(lds + pos2 * 72 + half * 32 + i * 8);
  } else {
    const long orowbase = (long)(bt * 16) << 11;
#pragma unroll
    for (int mt2 = 0; mt2 < 2; mt2++) {
      const int prow = w * 32 + mt2 * 16 + lm;
      f32x4 a2 = f32x4{0.f, 0.f, 0.f, 0.f};
#pragma unroll
      for (int kk = 0; kk < 2; kk++) {
        s16x8 af = *(const s16x8*)(lds + prow * 88 + kk * 32 + q * 8);
        a2 = __builtin_amdgcn_mfma_f32_16x16x32_bf16(af, tfrag[kk], a2, 0, 0, 0);
      }
      u16 ov[4];
#pragma unroll
      for (int r = 0; r < 4; r++) ov[r] = f2bf(a2[r]);
      *(uint2*)(out + orowbase + ((long)lm << 11) + n0 + w * 32 + mt2 * 16 + q * 4) =
          make_uint2((u32)ov[0] | ((u32)ov[1] << 16), (u32)ov[2] | ((u32)ov[3] << 16));
    }
  }
}

// ---------------------------------------------------------------------------
// CIN=16 conv (WK=64), R6-style single-bt block (best measured for CIN=16):
// stage 128 rows once, sync, 2 kk x 16 MFMA, epilogue via LDS(72).
// Output [n][16][TOUT][64].
// ---------------------------------------------------------------------------
template <int TIN>
__global__ __launch_bounds__(256, 3) void conv64_k(
    const u16* __restrict__ in, const u16* __restrict__ WcT,
    const float* __restrict__ bias, u16* __restrict__ out)
{
  constexpr int TOUT = TIN - 2;
  constexpr int ROWS = 16 * TIN * 16;
  __shared__ u16 lds[128 * 72];

  const int tid = threadIdx.x;
  const int lane = tid & 63;
  const int w = tid >> 6;
  const int lm = lane & 15, q = lane >> 4;
  const int pos0 = blockIdx.x << 7;
  const int n0 = pos0 & 2047;
  const int bt = pos0 >> 11;
  const int b = bt / TOUT, t = bt - b * TOUT;
  const long cbase = (long)n0 * ROWS + (b * TIN + t) * 16;

  // stage 128 patch rows (64 elems each), XOR-swizzled granules
  const int srow_off = lane >> 3;
  const int sgl = (lane & 7) ^ srow_off;
#pragma unroll
  for (int i = 0; i < 4; i++) {
    const int row = i * 32 + w * 8 + srow_off;
    async16(in + cbase + (long)row * ROWS + sgl * 8,
            lds + (i * 32 + w * 8) * 64);
  }

  s16x8 wf[2][2];
  {
    const u16* wp = WcT + (w * 16 + lm) * 64 + q * 8;
#pragma unroll
    for (int kk = 0; kk < 2; kk++) {
      wf[0][kk] = *(const s16x8*)(wp + kk * 32);
      wf[1][kk] = *(const s16x8*)(wp + 64 * 64 + kk * 32);
    }
  }
  const int c = w * 16 + lm;
  const float bsum = bias[c] + bias[64 + c];
  const float bg = bias[128 + c];

  f32x4 acc[8][2];
#pragma unroll
  for (int m = 0; m < 8; m++) {
    acc[m][0] = f32x4{0.f, 0.f, 0.f, 0.f};
    acc[m][1] = f32x4{0.f, 0.f, 0.f, 0.f};
  }

  __syncthreads();

#pragma unroll
  for (int kk = 0; kk < 2; kk++) {
    const int ph = ((kk * 4 + q) ^ (lm & 7));
#pragma unroll
    for (int mt = 0; mt < 8; mt++) {
      s16x8 pf = *(const s16x8*)(lds + (mt * 16 + lm) * 64 + ph * 8);
      acc[mt][0] = __builtin_amdgcn_mfma_f32_16x16x32_bf16(pf, wf[0][kk], acc[mt][0], 0, 0, 0);
      acc[mt][1] = __builtin_amdgcn_mfma_f32_16x16x32_bf16(pf, wf[1][kk], acc[mt][1], 0, 0, 0);
    }
  }

  __syncthreads();                    // all patch reads done; reuse LDS

#pragma unroll
  for (int mt = 0; mt < 8; mt++) {
#pragma unroll
    for (int r = 0; r < 4; r++) {
      const int pos = mt * 16 + q * 4 + r;
      const float temp = acc[mt][0][r] + bsum;
      const float ga = acc[mt][1][r] + bg;
      lds[pos * 72 + c] = f2bf(fmaxf(temp * sigmoidf(ga), 0.0f));
    }
  }
  __syncthreads();

  const int pos2 = tid >> 1, half = tid & 1;
  u16* orow = out + ((((long)(n0 + pos2) * 16 + b) * TOUT + t) << 6) + half * 32;
#pragma unroll
  for (int i = 0; i < 4; i++)
    *(uint4*)(orow + i * 8) = *(const uint4*)(lds + pos2 * 72 + half * 32 + i * 8);
}

// ---------------------------------------------------------------------------
// FC via MFMA: out4[b][n][p] = sum_k o3[(n*16+b)][k] * fwT[p][k] + fb[p]
// ---------------------------------------------------------------------------
__global__ __launch_bounds__(256) void fc_mfma(
    const u16* __restrict__ o3, const u16* __restrict__ fwT,
    const float* __restrict__ fb, float* __restrict__ out)
{
  __shared__ u16 sfw[16 * 896];
  const int tid = threadIdx.x;
#pragma unroll
  for (int i = 0; i < 7; i++)
    *(uint4*)(sfw + (i * 256 + tid) * 8) = *(const uint4*)(fwT + (i * 256 + tid) * 8);
  __syncthreads();

  const int lane = tid & 63, w = tid >> 6;
  const int lm = lane & 15, q = lane >> 4;
  const int row0 = blockIdx.x * 128 + w * 32;
  const u16* a0 = o3 + (long)(row0 + lm) * 896 + q * 8;
  const u16* bp = sfw + lm * 896 + q * 8;

  f32x4 acc0 = f32x4{0.f, 0.f, 0.f, 0.f};
  f32x4 acc1 = f32x4{0.f, 0.f, 0.f, 0.f};
#pragma unroll 7
  for (int kt = 0; kt < 28; kt++) {
    s16x8 af0 = *(const s16x8*)(a0 + kt * 32);
    s16x8 af1 = *(const s16x8*)(a0 + 16 * 896 + kt * 32);
    s16x8 bf = *(const s16x8*)(bp + kt * 32);
    acc0 = __builtin_amdgcn_mfma_f32_16x16x32_bf16(af0, bf, acc0, 0, 0, 0);
    acc1 = __builtin_amdgcn_mfma_f32_16x16x32_bf16(af1, bf, acc1, 0, 0, 0);
  }

  if (lm < 12) {
    const float bias = fb[lm];
#pragma unroll
    for (int r = 0; r < 4; r++) {
      const int row_a = row0 + q * 4 + r;
      out[((long)(row_a & 15) * 2048 + (row_a >> 4)) * 12 + lm] = acc0[r] + bias;
      const int row_b = row_a + 16;
      out[((long)(row_b & 15) * 2048 + (row_b >> 4)) * 12 + lm] = acc1[r] + bias;
    }
  }
}

// ---------------------------------------------------------------------------
extern "C" void kernel_launch(void* const* d_in, const int* in_sizes, int n_in,
                              void* d_out, int out_size, void* d_ws, size_t ws_size,
                              hipStream_t stream)
{
  const float* x    = (const float*)d_in[0];
  const float* A    = (const float*)d_in[1];
  const float* tb1w = (const float*)d_in[2];
  const float* tb1b = (const float*)d_in[3];
  const float* th1  = (const float*)d_in[4];
  const float* tb2w = (const float*)d_in[5];
  const float* tb2b = (const float*)d_in[6];
  const float* tb3w = (const float*)d_in[7];
  const float* tb3b = (const float*)d_in[8];
  const float* th2  = (const float*)d_in[9];
  const float* tb4w = (const float*)d_in[10];
  const float* tb4b = (const float*)d_in[11];
  const float* tb5w = (const float*)d_in[12];
  const float* tb5b = (const float*)d_in[13];
  const float* fw   = (const float*)d_in[14];
  const float* fb   = (const float*)d_in[15];
  float* out = (float*)d_out;

  char* ws = (char*)d_ws;
  u16* Abf  = (u16*)(ws + 0);            //  8,388,608 B
  u16* W2   = (u16*)(ws + 8388608);      //     16,384
  u16* W3   = (u16*)(ws + 8404992);      //     49,152
  u16* W4   = (u16*)(ws + 8454144);      //     16,384
  u16* W5   = (u16*)(ws + 8470528);      //     49,152
  u16* bufA = (u16*)(ws + 8519680);      // 92,274,688 (max live use 83.9 MB)
  u16* bufB = (u16*)(ws + 100794368);    // 92,274,688
  u16* W1   = (u16*)(ws + 8519680 + 88000000);  // 2 KB, in bufA tail slack
  u16* FWT  = (u16*)(ws + 8519680 + 88004096);  // 28,672 B, bufA tail slack

  prep_all<<<4412, 256, 0, stream>>>(A, Abf, out + 393216,
                                     tb1w, W1, tb2w, W2, tb3w, W3,
                                     tb4w, W4, tb5w, W5, fw, FWT);

  // ---- block 1:  U1 = TB1(x)*th1; t2 = relu(A*U1); out1 = TB2(t2)
  tb1_kernel<<<dim3(8, 16, 22), 256, 0, stream>>>(x, W1, tb1b, th1, bufA);
  sp_gemm<1><<<44 * 16, 256, 0, stream>>>(Abf, bufA, bufB, 5632);
  conv64_k<22><<<5120, 256, 0, stream>>>(bufB, W2, tb2b, bufA);              // -> [n][16][20][64]
  // ---- block 2:  U2 = TB3(out1)*th2 (fused); t2 = relu(A*U2); TB4(t2)
  conv192_k<20, 1><<<4608, 256, 0, stream>>>(bufA, W3, tb3b, th2, bufB);     // -> U2 [(b,t,p)][n]
  sp_gemm<1><<<36 * 16, 256, 0, stream>>>(Abf, bufB, bufA, 4608);
  conv64_k<18><<<4096, 256, 0, stream>>>(bufA, W4, tb4b, bufB);              // -> [n][16][16][64]
  // ---- tail
  conv192_k<16, 0><<<3584, 256, 0, stream>>>(bufB, W5, tb5b, nullptr, bufA); // -> [n][16][14][64]
  fc_mfma<<<256, 256, 0, stream>>>(bufA, FWT, fb, out);
}